// Round 1
// baseline (303.648 us; speedup 1.0000x reference)
//
#include <hip/hip_runtime.h>

// TTLinearR: y = x @ W^T + b, W (4096x4096) = TT ranks [1,64,64,64,64,64,1].
// W = Amat(4096,64) @ Bmat(64,4096):
//   Amat = ((c0r(16,64)@c1r(64,1024)).reshape(256,64)@c2r(64,1024)).reshape(4096,64)
//   S3(1024,16) = c4r(1024,64)@c5r(64,16); Bmat(64,4096) = (c3r(1024,64)@S3view(64,256)) flat
// y = (x @ Bmat^T) @ Amat^T + b.  Traffic floor ~258 MB (~41 us).
//
// R5: per-token-tile FUSION of both GEMMs. t-tile (32x64) for a 32-token block
// is tiny -> compute it locally (phase 1, K=4096 staged in LDS, rank x K-half
// wave split), keep in LDS as bf16, then stream Amat from L2 and write y
// (phase 2). Deletes t_part round-trip (32 MB), reduce_t, and 4 launches:
// 7 dispatches -> 3.

#define TOK 8192
#define DIN 4096
#define DOUT 4096
#define RNK 64

#define TB 32    // tokens per fused block
#define BK 256   // K per staged phase-1 iter
#define NKI (DIN / BK)   // 16
#define XS 264   // phase-1 LDS row stride (256 + 8 pad shorts): 33 quads == 1 mod 8
#define AS 72    // phase-2 LDS row stride (64 + 8 pad shorts): 9 quads == 1 mod 8
#define TSTR 66  // tred fp32 row stride

typedef __bf16 bf16x8 __attribute__((ext_vector_type(8)));
typedef float f32x4 __attribute__((ext_vector_type(4)));

__device__ __forceinline__ unsigned short f2bf(float f) {
  unsigned int u = __float_as_uint(f);
  u += 0x7FFFu + ((u >> 16) & 1u);  // RNE
  return (unsigned short)(u >> 16);
}

// ---- chain1: S1(16x1024) = c0(16,64)@c1(64,1024); S3(1024x16) = c4(1024,64)@c5(64,16)
__global__ void chain1(const float* __restrict__ c0, const float* __restrict__ c1,
                       const float* __restrict__ c4, const float* __restrict__ c5,
                       float* __restrict__ S1, float* __restrict__ S3) {
  int b = blockIdx.x;
  if (b < 64) {
    int idx = b * 256 + threadIdx.x;
    int m = idx >> 10, n = idx & 1023;
    const float* a = c0 + m * 64;
    float acc = 0.f;
#pragma unroll
    for (int k = 0; k < 64; ++k) acc += a[k] * c1[k * 1024 + n];
    S1[idx] = acc;
  } else {
    int idx = (b - 64) * 256 + threadIdx.x;
    int m = idx >> 4, n = idx & 15;
    const float* a = c4 + m * 64;
    float acc = 0.f;
#pragma unroll
    for (int k = 0; k < 64; ++k) acc += a[k] * c5[k * 16 + n];
    S3[idx] = acc;
  }
}

// ---- chain2: Abf = bf16(S1(256,64)@c2(64,1024)) == Amat(4096,64) flat;
//              Bbf = bf16(c3(1024,64)@S3view(64,256)) == Bmat(64,4096) flat
__global__ void chain2(const float* __restrict__ S1, const float* __restrict__ c2,
                       const float* __restrict__ c3, const float* __restrict__ S3,
                       unsigned short* __restrict__ Abf, unsigned short* __restrict__ Bbf) {
  int b = blockIdx.x;
  if (b < 1024) {
    int idx = b * 256 + threadIdx.x;
    int m = idx >> 10, n = idx & 1023;
    const float* a = S1 + m * 64;
    float acc = 0.f;
#pragma unroll
    for (int k = 0; k < 64; ++k) acc += a[k] * c2[k * 1024 + n];
    Abf[idx] = f2bf(acc);
  } else {
    int idx = (b - 1024) * 256 + threadIdx.x;
    int m = idx >> 8, n = idx & 255;
    const float* a = c3 + m * 64;
    float acc = 0.f;
#pragma unroll
    for (int k = 0; k < 64; ++k) acc += a[k] * S3[k * 256 + n];
    Bbf[idx] = f2bf(acc);
  }
}

// ---- fused: per 32-token block, t = x@Bmat^T (phase 1) then y = t@Amat^T + b (phase 2)
// 512 threads = 8 waves. Phase 1 wave split: jrank = wv&3 (16-rank tile),
// khalf = wv>>2 (K-half of each BK=256 tile). Phase 2: wave wv owns 64 output cols
// per 512-wide n-iter.
__global__ __launch_bounds__(512)
void fused_ttl(const float* __restrict__ x, const unsigned short* __restrict__ Bbf,
               const unsigned short* __restrict__ Abf, const float* __restrict__ bias,
               float* __restrict__ out) {
  // LDS union, 78336 B:
  //   ts   [0 .. 2304)            32 x AS bf16 t-tile (lives through phase 2)
  //   xs   [2304 .. 2304+8448)    32 x XS bf16 (phase 1)
  //   bs   [.. +16896)            64 x XS bf16 (phase 1)
  //   tred [2304 ..) fp32 32xTSTR (reduce step; overlaps xs/bs, barrier-separated)
  //   as_  [2304 .. 39168)        512 x AS bf16 Amat tile (phase 2; overlaps)
  __shared__ __align__(16) unsigned short sm[39168];
  unsigned short* ts = sm;
  unsigned short* xs = sm + 2304;
  unsigned short* bs = sm + 2304 + 32 * XS;
  float* tred = (float*)(sm + 2304);
  unsigned short* as_ = sm + 2304;

  const int tid = threadIdx.x;
  const int m0 = blockIdx.x * TB;
  const int lane = tid & 63, wv = tid >> 6;
  const int r = lane & 15, q = lane >> 4;
  const int khalf = wv >> 2, jrank = wv & 3;

  // staging index maps (fixed per thread)
  int xr[4], xc[4], br[4], bc[4];
#pragma unroll
  for (int j = 0; j < 4; ++j) {
    int f = j * 512 + tid;
    xr[j] = f >> 6; xc[j] = f & 63;   // 32 rows x 64 float4-chunks of x
    br[j] = f >> 5; bc[j] = f & 31;   // 64 rows x 32 uint4-chunks of Bmat
  }

  // ---------------- phase 1 ----------------
  float4 px[4]; uint4 pb[4];
#pragma unroll
  for (int j = 0; j < 4; ++j) {  // prefetch iter 0
    px[j] = *(const float4*)&x[(size_t)(m0 + xr[j]) * DIN + xc[j] * 4];
    pb[j] = *(const uint4*)&Bbf[(size_t)br[j] * DIN + bc[j] * 8];
  }

  f32x4 acc1[2];
#pragma unroll
  for (int i = 0; i < 2; ++i) acc1[i] = (f32x4){0.f, 0.f, 0.f, 0.f};

#pragma unroll 1
  for (int ki = 0; ki < NKI; ++ki) {
    __syncthreads();  // previous tile's readers done -> LDS writable
#pragma unroll
    for (int j = 0; j < 4; ++j) {
      ushort4 h = {f2bf(px[j].x), f2bf(px[j].y), f2bf(px[j].z), f2bf(px[j].w)};
      *(ushort4*)&xs[xr[j] * XS + xc[j] * 4] = h;
      *(uint4*)&bs[br[j] * XS + bc[j] * 8] = pb[j];
    }
    if (ki + 1 < NKI) {  // issue next tile's loads early (latency hides under MFMA+barrier)
      int k0n = (ki + 1) * BK;
#pragma unroll
      for (int j = 0; j < 4; ++j) {
        px[j] = *(const float4*)&x[(size_t)(m0 + xr[j]) * DIN + k0n + xc[j] * 4];
        pb[j] = *(const uint4*)&Bbf[(size_t)br[j] * DIN + k0n + bc[j] * 8];
      }
    }
    __syncthreads();  // tile ready
#pragma unroll
    for (int s32 = 0; s32 < 4; ++s32) {
      const int koff = khalf * 128 + s32 * 32 + q * 8;
      bf16x8 bfr = *(const bf16x8*)&bs[(jrank * 16 + r) * XS + koff];
#pragma unroll
      for (int i = 0; i < 2; ++i) {
        bf16x8 afr = *(const bf16x8*)&xs[(i * 16 + r) * XS + koff];
        acc1[i] = __builtin_amdgcn_mfma_f32_16x16x32_bf16(afr, bfr, acc1[i], 0, 0, 0);
      }
    }
  }

  // reduce K-halves: waves 4..7 dump partial t, waves 0..3 add + cvt -> ts
  // C/D: col = r (rank within 16-tile), row = q*4+g (token within 16-row frag)
  __syncthreads();
  if (wv >= 4) {
#pragma unroll
    for (int i = 0; i < 2; ++i)
#pragma unroll
      for (int g = 0; g < 4; ++g)
        tred[(i * 16 + q * 4 + g) * TSTR + jrank * 16 + r] = acc1[i][g];
  }
  __syncthreads();
  if (wv < 4) {
#pragma unroll
    for (int i = 0; i < 2; ++i)
#pragma unroll
      for (int g = 0; g < 4; ++g) {
        float v = acc1[i][g] + tred[(i * 16 + q * 4 + g) * TSTR + jrank * 16 + r];
        ts[(i * 16 + q * 4 + g) * AS + jrank * 16 + r] = f2bf(v);
      }
  }
  __syncthreads();

  // ---------------- phase 2 ----------------
#pragma unroll 1
  for (int ni = 0; ni < DOUT / 512; ++ni) {
    const int n0 = ni * 512;
    // stage Amat rows n0..n0+511 (64 KB from L2, fully coalesced)
#pragma unroll
    for (int j = 0; j < 8; ++j) {
      int f = j * 512 + tid;
      int row = f >> 3, c = f & 7;
      *(uint4*)&as_[row * AS + c * 8] =
          *(const uint4*)&Abf[(size_t)(n0 + row) * RNK + c * 8];
    }
    __syncthreads();

    f32x4 acc2[2][4];
#pragma unroll
    for (int i = 0; i < 2; ++i)
#pragma unroll
      for (int j = 0; j < 4; ++j) acc2[i][j] = (f32x4){0.f, 0.f, 0.f, 0.f};

#pragma unroll
    for (int s32 = 0; s32 < 2; ++s32) {
      bf16x8 a2[2], b2[4];
#pragma unroll
      for (int i = 0; i < 2; ++i)
        a2[i] = *(const bf16x8*)&ts[(i * 16 + r) * AS + s32 * 32 + q * 8];
#pragma unroll
      for (int j = 0; j < 4; ++j)
        b2[j] = *(const bf16x8*)&as_[(wv * 64 + j * 16 + r) * AS + s32 * 32 + q * 8];
#pragma unroll
      for (int i = 0; i < 2; ++i)
#pragma unroll
        for (int j = 0; j < 4; ++j)
          acc2[i][j] = __builtin_amdgcn_mfma_f32_16x16x32_bf16(a2[i], b2[j], acc2[i][j], 0, 0, 0);
    }

    float bb[4];
#pragma unroll
    for (int j = 0; j < 4; ++j) bb[j] = bias[n0 + wv * 64 + j * 16 + r];

#pragma unroll
    for (int i = 0; i < 2; ++i)
#pragma unroll
      for (int g = 0; g < 4; ++g) {
        size_t rowg = (size_t)(m0 + i * 16 + q * 4 + g) * DOUT;
#pragma unroll
        for (int j = 0; j < 4; ++j)
          out[rowg + n0 + wv * 64 + j * 16 + r] = acc2[i][j][g] + bb[j];
      }
    __syncthreads();  // before overwriting as_ next n-iter
  }
}

extern "C" void kernel_launch(void* const* d_in, const int* in_sizes, int n_in,
                              void* d_out, int out_size, void* d_ws, size_t ws_size,
                              hipStream_t stream) {
  const float* c0 = (const float*)d_in[0];
  const float* c1 = (const float*)d_in[1];
  const float* c2 = (const float*)d_in[2];
  const float* c3 = (const float*)d_in[3];
  const float* c4 = (const float*)d_in[4];
  const float* c5 = (const float*)d_in[5];
  const float* x  = (const float*)d_in[6];
  const float* bias = (const float*)d_in[7];
  float* out = (float*)d_out;

  char* ws = (char*)d_ws;
  float*          S1  = (float*)(ws);                        // 64 KB
  float*          S3  = (float*)(ws + (1u << 16));           // 64 KB
  unsigned short* Abf = (unsigned short*)(ws + (2u << 16));  // 512 KB
  unsigned short* Bbf = (unsigned short*)(ws + (2u << 16) + (1u << 19));  // 512 KB

  chain1<<<128, 256, 0, stream>>>(c0, c1, c4, c5, S1, S3);
  chain2<<<2048, 256, 0, stream>>>(S1, c2, c3, S3, Abf, Bbf);
  fused_ttl<<<256, 512, 0, stream>>>(x, Bbf, Abf, bias, out);
}